// Round 6
// baseline (654.344 us; speedup 1.0000x reference)
//
#include <hip/hip_runtime.h>

// GATTP: fully-fused pipeline.
//   k_prep : W_enc -> hi/lo bf16, Wcomb = W_gate@W_enc (gate folded into GEMM),
//            zero the pool/gsum accumulators (harness re-poisons ws each iter).
//   k_gemm : [xe|gate] = x @ [W_enc|Wcomb]^T + bias (dual-bf16 MFMA, BK=32,
//            4 blocks/CU, 1-deep register prefetch), then IN-KERNEL per-segment
//            reduction of exp(gate)*xe (no-max softmax: gate~N(0,1), exp<=~250,
//            shift-invariant) with one atomicAdd per (seg,h,d) run.
//   k_final: out = relu(pool/gsum), 0 for empty segments.
// xe/gate never touch global memory (saves 77 MB round-trip + a kernel).
// N=100000, Din=1024, D=64, H=32, B=512. Output fp32 [512, 2048].

typedef short bf16x8 __attribute__((ext_vector_type(8)));
typedef float f32x4 __attribute__((ext_vector_type(4)));

#define NUM_GRAPHS 512
#define DIN 1024
#define DENC 64
#define NH 32
#define NB 96    // B-tile rows: 64 enc cols + 32 gate cols
#define BK 32    // K-step: LDS 35.8 KB -> 4 blocks/CU
#define LDA 40   // bf16 pitch for A tiles (80 B rows, 16B-aligned)
#define LDB 40   // bf16 pitch for B tiles

__device__ __forceinline__ unsigned short f2bf(float f) {
    unsigned int u = __float_as_uint(f);
    return (unsigned short)((u + 0x7fffu + ((u >> 16) & 1u)) >> 16);
}
// split fp32 into hi/lo bf16 (RNE): hi + lo represents f to ~2^-18 rel.
__device__ __forceinline__ void split2(float f, unsigned short& h, unsigned short& l) {
    unsigned int u = __float_as_uint(f);
    unsigned int hb = (u + 0x7fffu + ((u >> 16) & 1u)) >> 16;
    h = (unsigned short)hb;
    float hf = __uint_as_float(hb << 16);
    l = f2bf(f - hf);
}

__device__ __forceinline__ int clampseg(int v) {
    return v < 0 ? 0 : (v >= NUM_GRAPHS ? NUM_GRAPHS - 1 : v);
}

// ---- prep: W_enc conv + Wcomb build/conv + zero accumulators ----
// blocks [0,64):      W_enc fp32 -> hi/lo bf16 (rows 0..63)
// blocks [64,96):     Wcomb[j,:] = W_gate[j,:]@W_enc -> rows 64..95; bcomb
// blocks [96,1136):   zero accp (4 MB) + accg (64 KB), contiguous
__global__ void k_prep(const float* __restrict__ W,      // W_enc [64,1024]
                       const float* __restrict__ Wg,     // W_gate [32,64]
                       const float* __restrict__ bg,     // b_gate [32]
                       const float* __restrict__ be,     // b_enc [64]
                       unsigned short* __restrict__ Wh,  // [96,1024]
                       unsigned short* __restrict__ Wl,  // [96,1024]
                       float* __restrict__ bcomb,        // [32]
                       float* __restrict__ accp)         // [512*2048 + 512*32]
{
    const int blk = blockIdx.x;
    const int tid = threadIdx.x;
    if (blk < 64) {
        int idx = (blk * 256 + tid) * 4;  // 65536 elems
        float4 v = *(const float4*)(W + idx);
        ushort4 h4, l4;
        split2(v.x, h4.x, l4.x);
        split2(v.y, h4.y, l4.y);
        split2(v.z, h4.z, l4.z);
        split2(v.w, h4.w, l4.w);
        *(ushort4*)(Wh + idx) = h4;
        *(ushort4*)(Wl + idx) = l4;
    } else if (blk < 96) {
        // Wcomb row j (one block per gate head)
        __shared__ float wgr[DENC];
        const int j = blk - 64;  // [0,32)
        if (tid < DENC) wgr[tid] = Wg[j * DENC + tid];
        __syncthreads();
        const int k0 = tid * 4;
        float4 a = {0.f, 0.f, 0.f, 0.f};
        for (int d = 0; d < DENC; ++d) {
            float w = wgr[d];
            float4 v = *(const float4*)(W + d * DIN + k0);
            a.x += w * v.x; a.y += w * v.y; a.z += w * v.z; a.w += w * v.w;
        }
        ushort4 h4, l4;
        split2(a.x, h4.x, l4.x);
        split2(a.y, h4.y, l4.y);
        split2(a.z, h4.z, l4.z);
        split2(a.w, h4.w, l4.w);
        *(ushort4*)(Wh + (DENC + j) * DIN + k0) = h4;
        *(ushort4*)(Wl + (DENC + j) * DIN + k0) = l4;
        if (tid == 0) {
            float s = bg[j];
            for (int d = 0; d < DENC; ++d) s += wgr[d] * be[d];
            bcomb[j] = s;
        }
    } else {
        // zero 512*2048 + 512*32 = 1064960 floats (accp then accg, contiguous)
        int idx = ((blk - 96) * 256 + tid) * 4;  // 1040 blocks * 1024 = exact
        *(float4*)(accp + idx) = (float4){0.f, 0.f, 0.f, 0.f};
    }
}

union SMem {
    struct { unsigned short Ah[128 * LDA]; unsigned short Al[128 * LDA];
             unsigned short Bh[NB * LDB];  unsigned short Bl[NB * LDB]; } s;   // 35840 B
    struct { float xs[64 * 68]; float gs[64 * 36]; int sg[128]; } e;           // 27136 B
};

// ----- [xe|gate] GEMM + fused per-segment exp-weighted pooling -----
// 128 rows/block, BK=32, 4 waves; wave w owns rows [32w,32w+32) x all 96 cols.
// Main loop identical to R4 (best so far). Epilogue: two 64-row halves; the
// owning 2 waves write xe / exp(gate) into LDS (union with staging), then all
// 4 waves reduce over rows (wave w -> heads [8w,8w+8), lane rl -> d=rl),
// flushing to global accumulators at segment boundaries via atomicAdd.
__global__ __launch_bounds__(256, 4) void k_gemm(
    const float* __restrict__ x,            // [N, 1024]
    const unsigned short* __restrict__ Wh,  // [96, 1024] bf16 hi
    const unsigned short* __restrict__ Wl,  // [96, 1024] bf16 lo
    const float* __restrict__ b_enc,        // [64]
    const float* __restrict__ bcomb,        // [32]
    const int* __restrict__ batch,          // [N] sorted segment ids
    float* __restrict__ accp,               // [512, 32, 64] pool accum
    float* __restrict__ accg,               // [512, 32] gsum accum
    int N)
{
    __shared__ SMem sm;

    const int tid  = threadIdx.x;
    const int lane = tid & 63;
    const int wv   = tid >> 6;
    const long brow = (long)blockIdx.x * 128;

    f32x4 acc[2][6];
    #pragma unroll
    for (int i = 0; i < 2; ++i)
        #pragma unroll
        for (int j = 0; j < 6; ++j) acc[i][j] = (f32x4){0.f, 0.f, 0.f, 0.f};

    const int arow = tid >> 1;
    const int ac16 = (tid & 1) * 16;
    const int fr  = lane & 15;          // fragment row/col within 16-tile
    const int fq  = lane >> 4;          // quad -> k sub-offset

    float4  va[4];
    ushort4 vbh[3], vbl[3];

    const long arowg = brow + arow;
    const bool arok = (arowg < N);
    const float* aptr = x + arowg * DIN + ac16;

    auto loadA = [&](int kc) {
        #pragma unroll
        for (int i = 0; i < 4; ++i)
            va[i] = arok ? *(const float4*)(aptr + kc + 4 * i)
                         : (float4){0.f, 0.f, 0.f, 0.f};
    };
    auto loadB = [&](int kc) {
        #pragma unroll
        for (int i = 0; i < 3; ++i) {
            int idx = tid + 256 * i;        // 0..767
            int row = idx >> 3;             // 0..95
            int c4  = (idx & 7) * 4;        // 0..28
            vbh[i] = *(const ushort4*)(Wh + row * DIN + kc + c4);
            vbl[i] = *(const ushort4*)(Wl + row * DIN + kc + c4);
        }
    };
    auto stageA = [&]() {
        #pragma unroll
        for (int i = 0; i < 4; ++i) {
            ushort4 h4, l4;
            split2(va[i].x, h4.x, l4.x);
            split2(va[i].y, h4.y, l4.y);
            split2(va[i].z, h4.z, l4.z);
            split2(va[i].w, h4.w, l4.w);
            *(ushort4*)&sm.s.Ah[arow * LDA + ac16 + 4 * i] = h4;
            *(ushort4*)&sm.s.Al[arow * LDA + ac16 + 4 * i] = l4;
        }
    };
    auto stageB = [&]() {
        #pragma unroll
        for (int i = 0; i < 3; ++i) {
            int idx = tid + 256 * i;
            int row = idx >> 3;
            int c4  = (idx & 7) * 4;
            *(ushort4*)&sm.s.Bh[row * LDB + c4] = vbh[i];
            *(ushort4*)&sm.s.Bl[row * LDB + c4] = vbl[i];
        }
    };
    auto mfmaPhase = [&]() {
        bf16x8 ah[2], al[2];
        #pragma unroll
        for (int rt = 0; rt < 2; ++rt) {
            int o = (wv * 32 + rt * 16 + fr) * LDA + fq * 8;
            ah[rt] = *(const bf16x8*)&sm.s.Ah[o];
            al[rt] = *(const bf16x8*)&sm.s.Al[o];
        }
        #pragma unroll
        for (int ct = 0; ct < 6; ++ct) {
            int o = (ct * 16 + fr) * LDB + fq * 8;
            bf16x8 bh = *(const bf16x8*)&sm.s.Bh[o];
            bf16x8 bl = *(const bf16x8*)&sm.s.Bl[o];
            #pragma unroll
            for (int rt = 0; rt < 2; ++rt) {
                acc[rt][ct] = __builtin_amdgcn_mfma_f32_16x16x32_bf16(ah[rt], bh, acc[rt][ct], 0, 0, 0);
                acc[rt][ct] = __builtin_amdgcn_mfma_f32_16x16x32_bf16(ah[rt], bl, acc[rt][ct], 0, 0, 0);
                acc[rt][ct] = __builtin_amdgcn_mfma_f32_16x16x32_bf16(al[rt], bh, acc[rt][ct], 0, 0, 0);
            }
        }
    };

    // ---- prologue: tile 0 in flight ----
    loadA(0);
    loadB(0);

    for (int k0 = 0; k0 < DIN; k0 += BK) {
        stageA();
        stageB();
        __syncthreads();
        const int kn = k0 + BK;
        if (kn < DIN) {
            loadA(kn);
            loadB(kn);
        }
        mfmaPhase();
        __syncthreads();
    }

    // ================= fused pooling epilogue =================
    // biases
    float bv[4], bcv[2];
    #pragma unroll
    for (int ct = 0; ct < 4; ++ct) bv[ct] = b_enc[ct * 16 + fr];
    #pragma unroll
    for (int j = 0; j < 2; ++j) bcv[j] = bcomb[j * 16 + fr];

    // segment ids for this block's rows (OOB rows -> last valid seg; their
    // exp-weight is forced to 0 below so they contribute nothing)
    if (tid < 128) {
        long gr = brow + tid;
        int  ix = (int)((gr < N) ? gr : (N - 1));
        sm.e.sg[tid] = clampseg(batch[ix]);
    }

    const int h0 = wv * 8;     // this wave's 8 heads
    const int rl = lane;       // this lane's d
    float pool[8], gp[8];

    auto flush = [&](int sgid) {
        if (gp[0] != 0.f) {    // gp uniform across lanes; 0 only for OOB-only runs
            float* pp = accp + ((long)sgid * NH + h0) * DENC + rl;
            #pragma unroll
            for (int j = 0; j < 8; ++j) {
                atomicAdd(pp + j * DENC, pool[j]);
                pool[j] = 0.f;
            }
            if (rl == 0) {
                #pragma unroll
                for (int j = 0; j < 8; ++j) {
                    atomicAdd(accg + sgid * NH + h0 + j, gp[j]);
                }
            }
        }
        #pragma unroll
        for (int j = 0; j < 8; ++j) gp[j] = 0.f;
    };

    #pragma unroll
    for (int half = 0; half < 2; ++half) {
        // -- write phase: waves {2*half, 2*half+1} own rows [64*half, 64*half+64)
        if ((wv >> 1) == half) {
            #pragma unroll
            for (int rt = 0; rt < 2; ++rt) {
                #pragma unroll
                for (int r = 0; r < 4; ++r) {
                    int  lr = (wv & 1) * 32 + rt * 16 + fq * 4 + r;   // [0,64)
                    long gr = brow + half * 64 + lr;
                    bool ok = (gr < N);
                    #pragma unroll
                    for (int ct = 0; ct < 4; ++ct)
                        sm.e.xs[lr * 68 + ct * 16 + fr] = acc[rt][ct][r] + bv[ct];
                    #pragma unroll
                    for (int j = 0; j < 2; ++j)
                        sm.e.gs[lr * 36 + j * 16 + fr] =
                            ok ? __expf(acc[rt][4 + j][r] + bcv[j]) : 0.f;
                }
            }
        }
        __syncthreads();

        // -- reduce phase: all 4 waves; flush at segment boundaries
        #pragma unroll
        for (int j = 0; j < 8; ++j) { pool[j] = 0.f; gp[j] = 0.f; }
        int cur = sm.e.sg[half * 64];
        for (int r2 = 0; r2 < 64; ++r2) {
            int s2 = sm.e.sg[half * 64 + r2];
            if (s2 != cur) { flush(cur); cur = s2; }
            float  xv = sm.e.xs[r2 * 68 + rl];
            float4 g1 = *(const float4*)&sm.e.gs[r2 * 36 + h0];
            float4 g2 = *(const float4*)&sm.e.gs[r2 * 36 + h0 + 4];
            pool[0] += g1.x * xv; pool[1] += g1.y * xv;
            pool[2] += g1.z * xv; pool[3] += g1.w * xv;
            pool[4] += g2.x * xv; pool[5] += g2.y * xv;
            pool[6] += g2.z * xv; pool[7] += g2.w * xv;
            gp[0] += g1.x; gp[1] += g1.y; gp[2] += g1.z; gp[3] += g1.w;
            gp[4] += g2.x; gp[5] += g2.y; gp[6] += g2.z; gp[7] += g2.w;
        }
        flush(cur);
        __syncthreads();   // before next half overwrites xs/gs
    }
}

// ---- final: out[b,h,d] = relu(pool/gsum), 0 for empty segments ----
__global__ __launch_bounds__(256) void k_final(
    const float* __restrict__ accp,   // [512, 2048]
    const float* __restrict__ accg,   // [512, 32]
    float* __restrict__ out)          // [512, 2048]
{
    const int b = blockIdx.x;
    const float* pp = accp + (long)b * (NH * DENC);
    float* oo = out + (long)b * (NH * DENC);
    #pragma unroll
    for (int it = 0; it < 8; ++it) {
        int i = threadIdx.x + 256 * it;
        float s = accg[b * NH + (i >> 6)];
        float v = (s > 0.f) ? pp[i] / s : 0.f;
        oo[i] = fmaxf(v, 0.f);
    }
}

extern "C" void kernel_launch(void* const* d_in, const int* in_sizes, int n_in,
                              void* d_out, int out_size, void* d_ws, size_t ws_size,
                              hipStream_t stream)
{
    const float* x      = (const float*)d_in[0];
    const int* batch    = (const int*)d_in[1];   // int64 in reference -> int32 from harness
    const float* W_enc  = (const float*)d_in[2];
    const float* b_enc  = (const float*)d_in[3];
    const float* W_gate = (const float*)d_in[4];
    const float* b_gate = (const float*)d_in[5];
    float* out = (float*)d_out;
    const int N = in_sizes[1];

    char* ws = (char*)d_ws;
    size_t off = 0;
    auto take = [&](size_t bytes) {
        char* p = ws + off;
        off += (bytes + 255) & ~(size_t)255;
        return p;
    };
    // accp (4 MB, 256-aligned multiple) immediately followed by accg so the
    // zeroing pass in k_prep can cover both with one contiguous sweep.
    float* accp = (float*)take((size_t)NUM_GRAPHS * NH * DENC * sizeof(float)); // 4 MB
    float* accg = (float*)take((size_t)NUM_GRAPHS * NH * sizeof(float));        // 64 KB
    unsigned short* Wh = (unsigned short*)take((size_t)NB * DIN * 2);
    unsigned short* Wl = (unsigned short*)take((size_t)NB * DIN * 2);
    float* bcomb = (float*)take(NH * sizeof(float));
    (void)ws_size; (void)n_in; (void)out_size;

    // 64 conv + 32 Wcomb + 1040 zero blocks
    k_prep<<<1136, 256, 0, stream>>>(W_enc, W_gate, b_gate, b_enc, Wh, Wl, bcomb, accp);
    k_gemm<<<(N + 127) / 128, 256, 0, stream>>>(x, Wh, Wl, b_enc, bcomb, batch, accp, accg, N);
    k_final<<<NUM_GRAPHS, 256, 0, stream>>>(accp, accg, out);
}

// Round 7
// 600.137 us; speedup vs baseline: 1.0903x; 1.0903x over previous
//
#include <hip/hip_runtime.h>

// GATTP: encoder+gate GEMM (dual-bf16 MFMA, A direct-from-global into
// registers — no A LDS staging; B LDS-staged per K-tile; BK=64; 64-row
// blocks; gate folded via Wcomb = W_gate@W_enc) -> per-segment
// online-softmax pooling (register-prefetch) -> ReLU.
// N=100000, Din=1024, D=64, H=32, B=512. Output fp32 [512, 2048].
// NOTE: harness delivers integer inputs as int32 (batch is const int*).

typedef short bf16x8 __attribute__((ext_vector_type(8)));
typedef float f32x4 __attribute__((ext_vector_type(4)));

#define NUM_GRAPHS 512
#define DIN 1024
#define DENC 64
#define NH 32
#define NB 96    // B-tile rows: 64 enc cols + 32 gate cols
#define BKG 64   // gemm K-step (16 iterations)
#define LDBG 72  // bf16 pitch for B tiles (144 B rows; 36-bank stride ->
                 // uniform 8-per-bank-group on b128 reads = conflict-free)

__device__ __forceinline__ unsigned short f2bf(float f) {
    unsigned int u = __float_as_uint(f);
    return (unsigned short)((u + 0x7fffu + ((u >> 16) & 1u)) >> 16);
}
// split fp32 into hi/lo bf16 (RNE): hi + lo represents f to ~2^-18 rel.
__device__ __forceinline__ void split2(float f, unsigned short& h, unsigned short& l) {
    unsigned int u = __float_as_uint(f);
    unsigned int hb = (u + 0x7fffu + ((u >> 16) & 1u)) >> 16;
    h = (unsigned short)hb;
    float hf = __uint_as_float(hb << 16);
    l = f2bf(f - hf);
}

__device__ __forceinline__ int clampseg(int v) {
    return v < 0 ? 0 : (v >= NUM_GRAPHS ? NUM_GRAPHS - 1 : v);
}

// ------- merged prep: segment offsets + W_enc conv + Wcomb build/conv -------
__global__ void k_prep(const int* __restrict__ batch, int* __restrict__ seg, int N,
                       const float* __restrict__ W,      // W_enc [64,1024]
                       const float* __restrict__ Wg,     // W_gate [32,64]
                       const float* __restrict__ bg,     // b_gate [32]
                       const float* __restrict__ be,     // b_enc [64]
                       unsigned short* __restrict__ Wh,  // [96,1024]
                       unsigned short* __restrict__ Wl,  // [96,1024]
                       float* __restrict__ bcomb,        // [32]
                       int nseg_blocks, int nconv_blocks)
{
    const int blk = blockIdx.x;
    const int tid = threadIdx.x;
    if (blk < nseg_blocks) {
        int n = blk * 256 + tid;
        if (n >= N) return;
        int bc = clampseg(batch[n]);
        if (n == 0) {
            for (int j = 0; j <= bc; ++j) seg[j] = 0;
            int bl = clampseg(batch[N - 1]);
            for (int j = bl + 1; j <= NUM_GRAPHS; ++j) seg[j] = N;
        } else {
            int bp = clampseg(batch[n - 1]);
            for (int j = bp + 1; j <= bc; ++j) seg[j] = n;
        }
    } else if (blk < nseg_blocks + nconv_blocks) {
        int idx = ((blk - nseg_blocks) * 256 + tid) * 4;  // 65536 elems
        float4 v = *(const float4*)(W + idx);
        ushort4 h4, l4;
        split2(v.x, h4.x, l4.x);
        split2(v.y, h4.y, l4.y);
        split2(v.z, h4.z, l4.z);
        split2(v.w, h4.w, l4.w);
        *(ushort4*)(Wh + idx) = h4;
        *(ushort4*)(Wl + idx) = l4;
    } else {
        // Wcomb row j (one block per gate head)
        __shared__ float wgr[DENC];
        const int j = blk - nseg_blocks - nconv_blocks;  // [0,32)
        if (tid < DENC) wgr[tid] = Wg[j * DENC + tid];
        __syncthreads();
        const int k0 = tid * 4;
        float4 a = {0.f, 0.f, 0.f, 0.f};
        for (int d = 0; d < DENC; ++d) {
            float w = wgr[d];
            float4 v = *(const float4*)(W + d * DIN + k0);
            a.x += w * v.x; a.y += w * v.y; a.z += w * v.z; a.w += w * v.w;
        }
        ushort4 h4, l4;
        split2(a.x, h4.x, l4.x);
        split2(a.y, h4.y, l4.y);
        split2(a.z, h4.z, l4.z);
        split2(a.w, h4.w, l4.w);
        *(ushort4*)(Wh + (DENC + j) * DIN + k0) = h4;
        *(ushort4*)(Wl + (DENC + j) * DIN + k0) = l4;
        if (tid == 0) {
            float s = bg[j];
            for (int d = 0; d < DENC; ++d) s += wgr[d] * be[d];
            bcomb[j] = s;
        }
    }
}

// ----- [xe | gate] = x @ [W_enc | Wcomb]^T + [b_enc | bcomb] (dual-bf16) ----
// 64 rows/block, 4 waves; wave w owns rows [16w, 16w+16) x all 96 cols.
// A path: global -> registers -> split2 -> MFMA (no LDS). Each lane (fr,fq)
// loads its own fragment rows directly; per-wave 1-deep register prefetch
// (convert current, then reload the same regs with next tile) spans both
// barriers since register loads need no vmcnt drain at s_barrier.
// B path: staged to LDS per BK=64 tile (L2-resident Wh/Wl), 2 barriers/iter.
__global__ __launch_bounds__(256, 4) void k_gemm(
    const float* __restrict__ x,            // [N, 1024]
    const unsigned short* __restrict__ Wh,  // [96, 1024] bf16 hi
    const unsigned short* __restrict__ Wl,  // [96, 1024] bf16 lo
    const float* __restrict__ b_enc,        // [64]
    const float* __restrict__ bcomb,        // [32]
    float* __restrict__ xe,                 // [N, 64]
    float* __restrict__ gate,               // [N, 32]
    int N)
{
    __shared__ unsigned short Bh[NB * LDBG], Bl[NB * LDBG];  // 27.6 KB

    const int tid  = threadIdx.x;
    const int lane = tid & 63;
    const int wv   = tid >> 6;
    const long brow = (long)blockIdx.x * 64;
    const int fr  = lane & 15;          // fragment row/col within 16-tile
    const int fq  = lane >> 4;          // quad -> k sub-offset

    f32x4 acc[6];
    #pragma unroll
    for (int j = 0; j < 6; ++j) acc[j] = (f32x4){0.f, 0.f, 0.f, 0.f};

    // this lane's A row (fragment row = fr)
    const long arow = brow + wv * 16 + fr;
    const bool aok  = (arow < N);
    const float* ap = x + arow * DIN + fq * 8;

    // va covers k = fq*8..fq*8+7 for kk=0 (va[0..1]) and kk=32 (va[2..3])
    float4 va[4];
    auto loadA = [&](int kc) {
        if (aok) {
            va[0] = *(const float4*)(ap + kc);
            va[1] = *(const float4*)(ap + kc + 4);
            va[2] = *(const float4*)(ap + kc + 32);
            va[3] = *(const float4*)(ap + kc + 36);
        } else {
            #pragma unroll
            for (int i = 0; i < 4; ++i) va[i] = (float4){0.f, 0.f, 0.f, 0.f};
        }
    };

    // B staging: 96 rows x 64 halfwords per buffer; 6 ushort4 chunks/thread.
    auto stageB = [&](int kc) {
        #pragma unroll
        for (int i = 0; i < 6; ++i) {
            int c   = tid + 256 * i;     // 0..1535
            int row = c >> 4;            // 0..95
            int c4  = (c & 15) * 4;      // 0..60
            *(ushort4*)&Bh[row * LDBG + c4] = *(const ushort4*)(Wh + row * DIN + kc + c4);
            *(ushort4*)&Bl[row * LDBG + c4] = *(const ushort4*)(Wl + row * DIN + kc + c4);
        }
    };

    // ---- prologue: A tile 0 in flight ----
    loadA(0);

    for (int k0 = 0; k0 < DIN; k0 += BKG) {
        stageB(k0);
        __syncthreads();

        // convert current A tile (waits on va), then reuse regs for next tile
        bf16x8 ah[2], al[2];
        #pragma unroll
        for (int K = 0; K < 2; ++K) {
            const float f[8] = { va[2*K].x, va[2*K].y, va[2*K].z, va[2*K].w,
                                 va[2*K+1].x, va[2*K+1].y, va[2*K+1].z, va[2*K+1].w };
            #pragma unroll
            for (int e = 0; e < 8; ++e) {
                unsigned short h, l;
                split2(f[e], h, l);
                ah[K][e] = (short)h;
                al[K][e] = (short)l;
            }
        }
        const int kn = k0 + BKG;
        if (kn < DIN) loadA(kn);   // flies under MFMA + barrier + next stageB

        #pragma unroll
        for (int ct = 0; ct < 6; ++ct) {
            #pragma unroll
            for (int K = 0; K < 2; ++K) {
                int o = (ct * 16 + fr) * LDBG + fq * 8 + K * 32;
                bf16x8 bh = *(const bf16x8*)&Bh[o];
                bf16x8 bl = *(const bf16x8*)&Bl[o];
                acc[ct] = __builtin_amdgcn_mfma_f32_16x16x32_bf16(ah[K], bh, acc[ct], 0, 0, 0);
                acc[ct] = __builtin_amdgcn_mfma_f32_16x16x32_bf16(ah[K], bl, acc[ct], 0, 0, 0);
                acc[ct] = __builtin_amdgcn_mfma_f32_16x16x32_bf16(al[K], bh, acc[ct], 0, 0, 0);
            }
        }
        __syncthreads();
    }

    // ---- epilogue: C layout col=lane&15, row=(lane>>4)*4+reg ----
    float bv[4], bcv[2];
    #pragma unroll
    for (int ct = 0; ct < 4; ++ct) bv[ct] = b_enc[ct * 16 + fr];
    #pragma unroll
    for (int j = 0; j < 2; ++j) bcv[j] = bcomb[j * 16 + fr];
    #pragma unroll
    for (int r = 0; r < 4; ++r) {
        long row = brow + wv * 16 + fq * 4 + r;
        if (row < N) {
            float* o = xe + row * DENC;
            #pragma unroll
            for (int ct = 0; ct < 4; ++ct)
                o[ct * 16 + fr] = acc[ct][r] + bv[ct];
            float* g = gate + row * NH;
            #pragma unroll
            for (int j = 0; j < 2; ++j)
                g[j * 16 + fr] = acc[4 + j][r] + bcv[j];
        }
    }
}

// ---------------- per-segment ONLINE softmax pooling + ReLU ----------------
// One block per segment. Wave w owns heads [8w, 8w+8); lane rl owns d=rl.
// Single pass; next chunk's xe/gate global loads issued before the d-loop
// (register prefetch) so HBM latency hides under compute.
__global__ __launch_bounds__(256) void k_pool(
    const float* __restrict__ xe,    // [N, 64]
    const float* __restrict__ gate,  // [N, 32]
    const int* __restrict__ seg,     // [513]
    float* __restrict__ out,         // [512, 2048]
    int N)
{
    __shared__ float xs[64 * 68];
    __shared__ float gs[64 * 36];
    const int tid = threadIdx.x;
    const int b = blockIdx.x;
    const int s = seg[b], e = seg[b + 1];
    const long ob = (long)b * (NH * DENC);
    if (e <= s) {
        for (int i = tid; i < NH * DENC; i += 256) out[ob + i] = 0.f;
        return;
    }
    const int rl = tid & 63;
    const int hq = tid >> 6;
    const int h0 = hq * 8;
    const int r0s = tid >> 4, c4 = (tid & 15) * 4;

    float m[8], pool[8], gp[8];
    #pragma unroll
    for (int j = 0; j < 8; ++j) { m[j] = -INFINITY; pool[j] = 0.f; gp[j] = 0.f; }

    float4 xv[4];
    float gv[8];
    auto load_chunk = [&](int base, int nrow) {
        #pragma unroll
        for (int i = 0; i < 4; ++i) {
            int row = r0s + 16 * i;
            xv[i] = (row < nrow)
                  ? *(const float4*)(xe + (long)(base + row) * DENC + c4)
                  : (float4){0.f, 0.f, 0.f, 0.f};
        }
        if (rl < nrow) {
            const float* g0 = gate + (long)(base + rl) * NH + h0;
            float4 a = *(const float4*)g0;
            float4 c = *(const float4*)(g0 + 4);
            gv[0] = a.x; gv[1] = a.y; gv[2] = a.z; gv[3] = a.w;
            gv[4] = c.x; gv[5] = c.y; gv[6] = c.z; gv[7] = c.w;
        } else {
            #pragma unroll
            for (int j = 0; j < 8; ++j) gv[j] = -INFINITY;
        }
    };

    load_chunk(s, min(64, e - s));

    for (int base = s; base < e; base += 64) {
        const int nrow = min(64, e - base);
        // chunk max per head, wave-uniform butterfly
        float cm[8];
        #pragma unroll
        for (int j = 0; j < 8; ++j) cm[j] = gv[j];
        #pragma unroll
        for (int off = 32; off > 0; off >>= 1)
            #pragma unroll
            for (int j = 0; j < 8; ++j) cm[j] = fmaxf(cm[j], __shfl_xor(cm[j], off));
        // online rescale (wave-uniform branch per head)
        #pragma unroll
        for (int j = 0; j < 8; ++j) {
            if (cm[j] > m[j]) {
                float sc = (m[j] == -INFINITY) ? 0.f : __expf(m[j] - cm[j]);
                pool[j] *= sc;
                gp[j]   *= sc;
                m[j] = cm[j];
            }
        }
        // g = exp(gate - m); invalid lanes hold -INF -> exp = 0
        float4 ga, gb;
        ga.x = __expf(gv[0] - m[0]); ga.y = __expf(gv[1] - m[1]);
        ga.z = __expf(gv[2] - m[2]); ga.w = __expf(gv[3] - m[3]);
        gb.x = __expf(gv[4] - m[4]); gb.y = __expf(gv[5] - m[5]);
        gb.z = __expf(gv[6] - m[6]); gb.w = __expf(gv[7] - m[7]);
        gp[0] += ga.x; gp[1] += ga.y; gp[2] += ga.z; gp[3] += ga.w;
        gp[4] += gb.x; gp[5] += gb.y; gp[6] += gb.z; gp[7] += gb.w;
        // stage xe chunk + gate weights to LDS
        #pragma unroll
        for (int i = 0; i < 4; ++i)
            *(float4*)&xs[(r0s + 16 * i) * 68 + c4] = xv[i];
        *(float4*)&gs[rl * 36 + h0] = ga;
        *(float4*)&gs[rl * 36 + h0 + 4] = gb;
        // prefetch next chunk (flies under the d-loop)
        int nb = base + 64;
        if (nb < e) load_chunk(nb, min(64, e - nb));
        __syncthreads();
        #pragma unroll 4
        for (int r2 = 0; r2 < nrow; ++r2) {
            float xvv = xs[r2 * 68 + rl];
            float4 g1 = *(const float4*)&gs[r2 * 36 + h0];
            float4 g2 = *(const float4*)&gs[r2 * 36 + h0 + 4];
            pool[0] += g1.x * xvv; pool[1] += g1.y * xvv;
            pool[2] += g1.z * xvv; pool[3] += g1.w * xvv;
            pool[4] += g2.x * xvv; pool[5] += g2.y * xvv;
            pool[6] += g2.z * xvv; pool[7] += g2.w * xvv;
        }
        __syncthreads();
    }
    // final gsum reduce (butterfly -> uniform) and output
    #pragma unroll
    for (int off = 32; off > 0; off >>= 1)
        #pragma unroll
        for (int j = 0; j < 8; ++j) gp[j] += __shfl_xor(gp[j], off);
    #pragma unroll
    for (int j = 0; j < 8; ++j) {
        float v = pool[j] / gp[j];
        out[ob + (h0 + j) * DENC + rl] = fmaxf(v, 0.f);
    }
}

extern "C" void kernel_launch(void* const* d_in, const int* in_sizes, int n_in,
                              void* d_out, int out_size, void* d_ws, size_t ws_size,
                              hipStream_t stream)
{
    const float* x      = (const float*)d_in[0];
    const int* batch    = (const int*)d_in[1];   // int64 in reference -> int32 from harness
    const float* W_enc  = (const float*)d_in[2];
    const float* b_enc  = (const float*)d_in[3];
    const float* W_gate = (const float*)d_in[4];
    const float* b_gate = (const float*)d_in[5];
    float* out = (float*)d_out;
    const int N = in_sizes[1];

    char* ws = (char*)d_ws;
    size_t off = 0;
    auto take = [&](size_t bytes) {
        char* p = ws + off;
        off += (bytes + 255) & ~(size_t)255;
        return p;
    };
    float* xe   = (float*)take((size_t)N * DENC * sizeof(float));   // 25.6 MB
    float* gate = (float*)take((size_t)N * NH * sizeof(float));     // 12.8 MB
    unsigned short* Wh = (unsigned short*)take((size_t)NB * DIN * 2);
    unsigned short* Wl = (unsigned short*)take((size_t)NB * DIN * 2);
    float* bcomb = (float*)take(NH * sizeof(float));
    int* seg = (int*)take((NUM_GRAPHS + 1) * sizeof(int));
    (void)ws_size; (void)n_in; (void)out_size;

    const int nseg_blocks  = (N + 255) / 256;
    const int nconv_blocks = (DENC * DIN) / 1024;   // 64
    k_prep<<<nseg_blocks + nconv_blocks + NH, 256, 0, stream>>>(
        batch, seg, N, W_enc, W_gate, b_gate, b_enc, Wh, Wl, bcomb, nseg_blocks, nconv_blocks);
    k_gemm<<<(N + 63) / 64, 256, 0, stream>>>(x, Wh, Wl, b_enc, bcomb, xe, gate, N);
    k_pool<<<NUM_GRAPHS, 256, 0, stream>>>(xe, gate, seg, out, N);
}